// Round 14
// baseline (2200.170 us; speedup 1.0000x reference)
//
#include <hip/hip_runtime.h>
#include <math.h>
#include <stdint.h>

#define Bz 64
#define Tz 32
#define Ez 64
#define Hz 256
#define Vz 32000
#define KTOT 320
#define LCAP 2048      // candidate list slots per row
#define THRC 0.02f     // THR = THRC * ||h_row||2 * max_c ||w_c||2  (sound bound: 0.0158)

typedef unsigned long long u64;
typedef unsigned int u32;
typedef unsigned short u16;

__device__ __forceinline__ u32 map_f32(float f) {
  u32 u = __float_as_uint(f);
  return (u & 0x80000000u) ? ~u : (u | 0x80000000u);
}
__device__ __forceinline__ float unmap_f32(u32 u) {
  return __uint_as_float((u & 0x80000000u) ? (u & 0x7FFFFFFFu) : ~u);
}
__device__ __forceinline__ u16 f2bf(float f) {   // RNE bf16
  u32 u = __float_as_uint(f);
  return (u16)((u + 0x7FFFu + ((u >> 16) & 1u)) >> 16);
}
__device__ __forceinline__ void gload_lds16(const float* g, float* l) {
  __builtin_amdgcn_global_load_lds(
      (const __attribute__((address_space(1))) void*)g,
      (__attribute__((address_space(3))) void*)l, 16, 0, 0);
}
__device__ __forceinline__ void gload_lds16u(const u16* g, u16* l) {
  __builtin_amdgcn_global_load_lds(
      (const __attribute__((address_space(1))) void*)g,
      (__attribute__((address_space(3))) void*)l, 16, 0, 0);
}

// ---------------- weight repack P4[j][k][g]; zero key/cnt/gmax/wn2 -----------------------
__global__ void k_prep(const float* __restrict__ Wi, const float* __restrict__ Ui,
                       const float* __restrict__ Wf, const float* __restrict__ Uf,
                       const float* __restrict__ Wog, const float* __restrict__ Uog,
                       const float* __restrict__ Wc, const float* __restrict__ Uc,
                       float* __restrict__ P4, u64* __restrict__ key,
                       int* __restrict__ cnt, u32* __restrict__ gmax,
                       u32* __restrict__ wn2) {
  int j = blockIdx.x, k = threadIdx.x;
  float g0, g1, g2, g3;
  if (k < Ez) {
    g0 = Wi[k*Hz + j]; g1 = Wf[k*Hz + j]; g2 = Wog[k*Hz + j]; g3 = Wc[k*Hz + j];
  } else {
    int kk = k - Ez;
    g0 = Ui[kk*Hz + j]; g1 = Uf[kk*Hz + j]; g2 = Uog[kk*Hz + j]; g3 = Uc[kk*Hz + j];
  }
  float* p = P4 + ((size_t)j*KTOT + k)*4;
  p[0] = g0; p[1] = g1; p[2] = g2; p[3] = g3;
  if (j == 0 && k < 2*Bz) key[k] = 0ull;
  if (j == 1 && k < Bz)   cnt[k] = 0;
  if (j == 2 && k < Bz)   gmax[k] = 0u;
  if (j == 3 && k == 0)   *wn2 = 0u;
}

// ---------------- Wo -> tiled bf16 Wb[tile][k][128]; max col-norm^2 ----------------------
__global__ __launch_bounds__(512) void wb_prep(const float* __restrict__ Wo,
                                               u16* __restrict__ Wb,
                                               u32* __restrict__ wn2) {
  __shared__ float cnorm[128];
  int bid = blockIdx.x, tid = threadIdx.x;
  const float* src = Wo + bid*128;
  u16* dst = Wb + (size_t)bid*32768;
  for (int idx = tid; idx < 32768; idx += 512) {
    int k = idx >> 7, c = idx & 127;
    dst[idx] = f2bf(src[(size_t)k*Vz + c]);
  }
  if (tid < 128) {
    float s = 0.f;
    for (int k = 0; k < Hz; ++k) {
      float w = src[(size_t)k*Vz + tid];
      s = fmaf(w, w, s);
    }
    cnorm[tid] = s;
  }
  __syncthreads();
  if (tid == 0) {
    float m = cnorm[0];
    for (int i = 1; i < 128; ++i) m = fmaxf(m, cnorm[i]);
    atomicMax(wn2, map_f32(m));
  }
}

// ---------------- per-step LSTM cell: 64 blocks x 512 thr (R12 + tok-mode + hTb) ---------
__global__ __launch_bounds__(512) void k_gates(
    int t, const int* __restrict__ gnp,
    const int* __restrict__ input_x, const int* __restrict__ start_tok,
    const float* __restrict__ emb, const float* __restrict__ P4,
    const float* __restrict__ bi_, const float* __restrict__ bf_,
    const float* __restrict__ bog_, const float* __restrict__ bc_,
    const float* __restrict__ hT_in, float* __restrict__ hT_out,
    u16* __restrict__ hTb_out, float* __restrict__ cT,
    const u64* __restrict__ key_prev, u64* __restrict__ key_cur,
    const int* __restrict__ tokp, int mode,
    int* __restrict__ out) {
  extern __shared__ float sm[];
  float* xh = sm;                        // 20480 f
  float* pw = sm + 20480;                // 5120 f
  float* sc = sm + 25600;                // 1024 f
  int*   tok_s = (int*)(sm + 26624);     // 64

  int tid = threadIdx.x;
  int blk = blockIdx.x;
  int gn = *gnp;

  if (tid < Bz) {
    int b = tid, tk;
    if (t == 0)          tk = start_tok[b];
    else if (t - 1 < gn) tk = input_x[b*Tz + (t-1)];
    else                 tk = mode ? tokp[b]
                              : (int)(~(u32)(key_prev[b] & 0xFFFFFFFFull));
    tok_s[b] = tk;
    if (blk == 0 && t > 0) out[b*Tz + (t-1)] = tk;
  }
  if (blk == 0 && tid >= 64 && tid < 64 + Bz) key_cur[tid - 64] = 0ull;
  __syncthreads();

  {
    int b = tid & 63, part = tid >> 6;
    const float4* e4 = (const float4*)(emb + (size_t)tok_s[b]*Ez + part*8);
    float4 v0 = e4[0], v1 = e4[1];
    int k0 = part*8;
    xh[(k0+0)*Bz + b] = v0.x; xh[(k0+1)*Bz + b] = v0.y;
    xh[(k0+2)*Bz + b] = v0.z; xh[(k0+3)*Bz + b] = v0.w;
    xh[(k0+4)*Bz + b] = v1.x; xh[(k0+5)*Bz + b] = v1.y;
    xh[(k0+6)*Bz + b] = v1.z; xh[(k0+7)*Bz + b] = v1.w;
  }
  if (t > 0) {
    const float4* s4 = (const float4*)hT_in;
    float4* d4 = (float4*)(xh + Ez*Bz);
    #pragma unroll
    for (int i = 0; i < 8; ++i) d4[tid + i*512] = s4[tid + i*512];
  }
  {
    const float* psrc = P4 + (size_t)blk*5120;
    #pragma unroll
    for (int i = 0; i < 10; ++i) pw[tid + i*512] = psrc[tid + i*512];
  }
  __syncthreads();

  int wid = tid >> 6, lane = tid & 63;
  int j4 = wid >> 1, seg = wid & 1;
  int j = blk*4 + j4;
  const float* wrow = pw + j4*1280;
  int kbeg = seg ? 160 : 0;
  int kend = (t > 0) ? (seg ? 320 : 160) : (seg ? 0 : 64);

  float ai = 0.f, af = 0.f, ao = 0.f, ac = 0.f;
  #pragma unroll 2
  for (int k = kbeg; k < kend; k += 4) {
    #pragma unroll
    for (int kk = 0; kk < 4; ++kk) {
      float4 wv = *(const float4*)(wrow + (k+kk)*4);
      float xv = xh[(k+kk)*Bz + lane];
      ai = fmaf(xv, wv.x, ai); af = fmaf(xv, wv.y, af);
      ao = fmaf(xv, wv.z, ao); ac = fmaf(xv, wv.w, ac);
    }
  }

  if (seg == 1) {
    sc[j4*256 +   0 + lane] = ai;
    sc[j4*256 +  64 + lane] = af;
    sc[j4*256 + 128 + lane] = ao;
    sc[j4*256 + 192 + lane] = ac;
  }
  __syncthreads();
  if (seg == 0) {
    ai += sc[j4*256 +   0 + lane] + bi_[j];
    af += sc[j4*256 +  64 + lane] + bf_[j];
    ao += sc[j4*256 + 128 + lane] + bog_[j];
    ac += sc[j4*256 + 192 + lane] + bc_[j];
    float gi = 1.f/(1.f + expf(-ai));
    float gf = 1.f/(1.f + expf(-af));
    float go = 1.f/(1.f + expf(-ao));
    float gc = tanhf(ac);
    float cold = (t > 0) ? cT[j*Bz + lane] : 0.f;
    float cn = gf*cold + gi*gc;
    float hn = go * tanhf(cn);
    cT[j*Bz + lane]       = cn;
    hT_out[j*Bz + lane]   = hn;
    hTb_out[j*Bz + lane]  = f2bf(hn);
  }
}

// ---------------- phase-1 logits (bf16) + adaptive-THR candidate emit --------------------
__global__ __launch_bounds__(512, 1) void k_logits_b(
    int t, const int* __restrict__ gnp,
    const u16* __restrict__ hTb,         // [k][b] bf16
    const u16* __restrict__ Wb,          // tiled [tile][k][128] bf16
    const float* __restrict__ bo,
    const u32* __restrict__ wn2p, float* __restrict__ rn2_g,
    u32* __restrict__ gmax,
    u64* __restrict__ list, int* __restrict__ cnt) {
  int gn = *gnp;
  if (t < gn) return;
  extern __shared__ float sm[];
  u16* hLDSb = (u16*)sm;                 // bytes 0..32768
  u16* wbuf  = (u16*)sm + 16384;         // bytes 32768..49152
  float* rnp  = sm + 12288;              // bytes 49152..51200 (8x64 f)
  float* rn2l = sm + 12800;              // bytes 51200..51456 (64 f)

  int tid = threadIdx.x;
  int bid = blockIdx.x;
  int wid = tid >> 6, lane = tid & 63;
  int seg = wid >> 1, chalf = wid & 1;
  int rg = lane >> 3, cg = lane & 7;

  float wn = sqrtf(unmap_f32(*wn2p));

  float bo8[8];
  {
    const float4* b4 = (const float4*)(bo + bid*128 + chalf*64 + cg*8);
    float4 x = b4[0], y = b4[1];
    bo8[0]=x.x; bo8[1]=x.y; bo8[2]=x.z; bo8[3]=x.w;
    bo8[4]=y.x; bo8[5]=y.y; bo8[6]=y.z; bo8[7]=y.w;
  }
  // stage bf16 h -> LDS (32 KB)
  {
    const uint4* s4 = (const uint4*)hTb;
    uint4* d4 = (uint4*)hLDSb;
    #pragma unroll
    for (int i = 0; i < 4; ++i) d4[tid + i*512] = s4[tid + i*512];
  }
  __syncthreads();

  // per-row ||h||^2 from staged bf16 h
  {
    int b = tid & 63, part = tid >> 6;
    float s = 0.f;
    #pragma unroll 8
    for (int k = part*32; k < part*32 + 32; ++k) {
      float v = __uint_as_float((u32)hLDSb[k*Bz + b] << 16);
      s = fmaf(v, v, s);
    }
    rnp[part*64 + b] = s;
  }
  __syncthreads();
  if (tid < 64) {
    float s = 0.f;
    #pragma unroll
    for (int p = 0; p < 8; ++p) s += rnp[p*64 + tid];
    rn2l[tid] = s;
    rn2_g[tid] = s;                      // identical value from every block: benign
  }
  __syncthreads();

  float thr8[8];
  if (wid < 2) {
    #pragma unroll
    for (int rr = 0; rr < 8; ++rr)
      thr8[rr] = THRC * sqrtf(rn2l[rg*8 + rr]) * wn;
  }

  float acc[8][8] = {};
  u16* wb = wbuf + wid*1024;             // 2 slots x 512 u16
  const u16* gW = Wb + (size_t)bid*32768 + chalf*64 + (lane & 7)*8
                + (size_t)(seg*64 + (lane >> 3))*128;

#define STAGE(q_, s_) gload_lds16u(gW + (size_t)(q_)*8*128, wb + (s_)*512);

#define COMPUTE(q_, s_) { \
    const u16* wp = wb + (s_)*512; \
    const u16* hp = hLDSb + (seg*64 + (q_)*8)*Bz + rg*8; \
    _Pragma("unroll") \
    for (int kk = 0; kk < 8; ++kk) { \
      uint4 hq = *(const uint4*)(hp + kk*Bz); \
      uint4 wq = *(const uint4*)(wp + kk*64 + cg*8); \
      float hv[8], wv[8]; \
      hv[0]=__uint_as_float(hq.x<<16); hv[1]=__uint_as_float(hq.x&0xFFFF0000u); \
      hv[2]=__uint_as_float(hq.y<<16); hv[3]=__uint_as_float(hq.y&0xFFFF0000u); \
      hv[4]=__uint_as_float(hq.z<<16); hv[5]=__uint_as_float(hq.z&0xFFFF0000u); \
      hv[6]=__uint_as_float(hq.w<<16); hv[7]=__uint_as_float(hq.w&0xFFFF0000u); \
      wv[0]=__uint_as_float(wq.x<<16); wv[1]=__uint_as_float(wq.x&0xFFFF0000u); \
      wv[2]=__uint_as_float(wq.y<<16); wv[3]=__uint_as_float(wq.y&0xFFFF0000u); \
      wv[4]=__uint_as_float(wq.z<<16); wv[5]=__uint_as_float(wq.z&0xFFFF0000u); \
      wv[6]=__uint_as_float(wq.w<<16); wv[7]=__uint_as_float(wq.w&0xFFFF0000u); \
      _Pragma("unroll") \
      for (int r = 0; r < 8; ++r) { \
        _Pragma("unroll") \
        for (int c = 0; c < 8; ++c) acc[r][c] = fmaf(hv[r], wv[c], acc[r][c]); } \
    } }

  STAGE(0, 0)
  #pragma unroll 1
  for (int q = 0; q < 7; ++q) {
    STAGE(q+1, (q+1)&1)
    asm volatile("s_waitcnt vmcnt(1)" ::: "memory");
    __builtin_amdgcn_sched_barrier(0);
    COMPUTE(q, q&1)
  }
  asm volatile("s_waitcnt vmcnt(0)" ::: "memory");
  __builtin_amdgcn_sched_barrier(0);
  COMPUTE(7, 1)
#undef STAGE
#undef COMPUTE

  // ---- merge k-segment partials ----
  float* scratch = sm;                   // 4 regions x 4096 f
  __syncthreads();
  if (wid >= 4) {
    float* r = scratch + (wid-4)*4096;
    #pragma unroll
    for (int i = 0; i < 64; ++i) r[i*64 + lane] = acc[i>>3][i&7];
  }
  __syncthreads();
  if (wid < 4) {
    const float* r = scratch + wid*4096;
    #pragma unroll
    for (int i = 0; i < 64; ++i) acc[i>>3][i&7] += r[i*64 + lane];
  }
  __syncthreads();
  if (wid == 2 || wid == 3) {
    float* r = scratch + (wid-2)*4096;
    #pragma unroll
    for (int i = 0; i < 64; ++i) r[i*64 + lane] = acc[i>>3][i&7];
  }
  __syncthreads();

  if (wid < 2) {
    const float* r = scratch + wid*4096;
    #pragma unroll
    for (int i = 0; i < 64; ++i) acc[i>>3][i&7] += r[i*64 + lane];

    int cbase = bid*128 + chalf*64 + cg*8;
    #pragma unroll
    for (int rr = 0; rr < 8; ++rr) {
      float bv = acc[rr][0] + bo8[0];
      #pragma unroll
      for (int c = 1; c < 8; ++c) bv = fmaxf(bv, acc[rr][c] + bo8[c]);
      #pragma unroll
      for (int m = 1; m < 8; m <<= 1) bv = fmaxf(bv, __shfl_xor(bv, m, 64));
      int row = rg*8 + rr;
      // running global max: emit threshold only tightens as gmax grows (order-safe)
      float cur = 0.f;
      if (cg == 0) {
        u32 old = atomicMax(&gmax[row], map_f32(bv));
        cur = fmaxf(unmap_f32(old), bv);
      }
      float thrw = __shfl(cur, rg*8, 64) - thr8[rr];
      #pragma unroll
      for (int c = 0; c < 8; ++c) {
        float v = acc[rr][c] + bo8[c];
        if (v >= thrw) {
          int idx = atomicAdd(&cnt[row], 1);
          if (idx < LCAP)
            list[(size_t)row*LCAP + idx] =
                ((u64)map_f32(v) << 32) | (u32)(~(u32)(cbase + c));
        }
      }
    }
  }
}

// ---------------- phase-2: exact f32 re-eval of candidates -> token ----------------------
__global__ __launch_bounds__(256) void k_pick(
    int t, const int* __restrict__ gnp,
    const float* __restrict__ hT,        // [k][b] f32
    const float* __restrict__ Wo, const float* __restrict__ bo,
    const u32* __restrict__ wn2p, const float* __restrict__ rn2_g,
    u64* __restrict__ list, int* __restrict__ cnt, u32* __restrict__ gmax,
    int* __restrict__ tok) {
  int gn = *gnp;
  if (t < gn) return;
  int b = blockIdx.x, tid = threadIdx.x;
  __shared__ u64 smax[4];
  __shared__ u64 sbest[4];
  __shared__ int scol[128];
  __shared__ int scnt;

  float wn = sqrtf(unmap_f32(*wn2p));
  float thrb = THRC * sqrtf(rn2_g[b]) * wn;

  int n = cnt[b]; if (n > LCAP) n = LCAP;
  const u64* L = list + (size_t)b*LCAP;
  if (tid == 0) scnt = 0;

  u64 m = 0;
  for (int i = tid; i < n; i += 256) { u64 v = L[i]; if (v > m) m = v; }
  #pragma unroll
  for (int s = 1; s < 64; s <<= 1) {
    u64 o = __shfl_xor(m, s, 64);
    if (o > m) m = o;
  }
  if ((tid & 63) == 0) smax[tid >> 6] = m;
  __syncthreads();
  u64 gm = smax[0];
  #pragma unroll
  for (int s = 1; s < 4; ++s) if (smax[s] > gm) gm = smax[s];
  float thr = unmap_f32((u32)(gm >> 32)) - thrb;

  for (int i = tid; i < n; i += 256) {
    u64 v = L[i];
    if (unmap_f32((u32)(v >> 32)) >= thr) {
      int s = atomicAdd(&scnt, 1);
      if (s < 128) scol[s] = (int)(~(u32)(v & 0xFFFFFFFFull));
    }
  }
  __syncthreads();
  int ns = scnt < 128 ? scnt : 128;

  int w = tid >> 6, lane = tid & 63;
  float bestv = -3.4e38f; int bestc = 0x7FFFFFFF;
  for (int base = 0; base < ns; base += 4) {
    int ci = base + w;
    if (ci < ns) {
      int c = scol[ci];
      int k0 = lane*4;
      float pv = 0.f;
      #pragma unroll
      for (int i = 0; i < 4; ++i)
        pv = fmaf(hT[(k0+i)*Bz + b], Wo[(size_t)(k0+i)*Vz + c], pv);
      #pragma unroll
      for (int s = 1; s < 64; s <<= 1) pv += __shfl_xor(pv, s, 64);
      pv += bo[c];
      if (pv > bestv || (pv == bestv && c < bestc)) { bestv = pv; bestc = c; }
    }
  }
  if (lane == 0)
    sbest[w] = ((u64)map_f32(bestv) << 32) | (u32)(~(u32)bestc);
  __syncthreads();
  if (tid == 0) {
    u64 bb = sbest[0];
    #pragma unroll
    for (int s = 1; s < 4; ++s) if (sbest[s] > bb) bb = sbest[s];
    tok[b]  = (int)(~(u32)(bb & 0xFFFFFFFFull));
    cnt[b]  = 0;                         // reset for next generation step
    gmax[b] = 0u;
  }
}

// ---------------- fallback f32 logits (byte-identical to round 12) -----------------------
__global__ __launch_bounds__(512, 1) void k_logits_f32(
    int t, const int* __restrict__ gnp,
    const float* __restrict__ hT,
    const float* __restrict__ Wo, const float* __restrict__ bo,
    u64* __restrict__ key_cur) {
  int gn = *gnp;
  if (t < gn) return;
  extern __shared__ float sm[];
  float* hLDS = sm;
  float* wbuf = sm + 16384;

  int tid = threadIdx.x;
  int bid = blockIdx.x;
  int wid = tid >> 6, lane = tid & 63;
  int seg = wid >> 1, chalf = wid & 1;
  int rg = lane >> 3, cg = lane & 7;

  float bo8[8];
  {
    const float4* b4 = (const float4*)(bo + bid*128 + chalf*64 + cg*8);
    float4 x = b4[0], y = b4[1];
    bo8[0]=x.x; bo8[1]=x.y; bo8[2]=x.z; bo8[3]=x.w;
    bo8[4]=y.x; bo8[5]=y.y; bo8[6]=y.z; bo8[7]=y.w;
  }
  {
    const float4* s4 = (const float4*)hT;
    float4* d4 = (float4*)hLDS;
    #pragma unroll
    for (int i = 0; i < 8; ++i) d4[tid + i*512] = s4[tid + i*512];
  }
  __syncthreads();

  float acc[8][8] = {};
  float* wb = wbuf + wid*2048;
  const float* gW = Wo + bid*128;

#define STAGE(q_, p_) { \
    int kb = seg*64 + (q_)*8; \
    _Pragma("unroll") \
    for (int i = 0; i < 4; ++i) { \
      int row = kb + i*2 + (lane>>5); \
      gload_lds16(gW + (size_t)row*Vz + ((lane&31)<<2), wb + (p_)*1024 + i*256); \
    } }

#define COMPUTE(q_, p_) { \
    const float* wp = wb + (p_)*1024; \
    const float* hp = hLDS + (seg*64 + (q_)*8)*Bz + rg*8; \
    _Pragma("unroll") \
    for (int kk = 0; kk < 8; ++kk) { \
      float4 h0 = *(const float4*)(hp + kk*Bz); \
      float4 h1 = *(const float4*)(hp + kk*Bz + 4); \
      float4 w0 = *(const float4*)(wp + kk*128 + chalf*64 + cg*8); \
      float4 w1 = *(const float4*)(wp + kk*128 + chalf*64 + cg*8 + 4); \
      float hv[8] = {h0.x,h0.y,h0.z,h0.w,h1.x,h1.y,h1.z,h1.w}; \
      float wv[8] = {w0.x,w0.y,w0.z,w0.w,w1.x,w1.y,w1.z,w1.w}; \
      _Pragma("unroll") \
      for (int r = 0; r < 8; ++r) { \
        _Pragma("unroll") \
        for (int c = 0; c < 8; ++c) acc[r][c] = fmaf(hv[r], wv[c], acc[r][c]); } \
    } }

  STAGE(0, 0)
  #pragma unroll 1
  for (int q = 0; q < 7; ++q) {
    STAGE(q+1, (q+1)&1)
    asm volatile("s_waitcnt vmcnt(4)" ::: "memory");
    __builtin_amdgcn_sched_barrier(0);
    COMPUTE(q, q&1)
  }
  asm volatile("s_waitcnt vmcnt(0)" ::: "memory");
  __builtin_amdgcn_sched_barrier(0);
  COMPUTE(7, 1)
#undef STAGE
#undef COMPUTE

  float* scratch = wbuf;
  __syncthreads();
  if (wid >= 4) {
    float* r = scratch + (wid-4)*4096;
    #pragma unroll
    for (int i = 0; i < 64; ++i) r[i*64 + lane] = acc[i>>3][i&7];
  }
  __syncthreads();
  if (wid < 4) {
    const float* r = scratch + wid*4096;
    #pragma unroll
    for (int i = 0; i < 64; ++i) acc[i>>3][i&7] += r[i*64 + lane];
  }
  __syncthreads();
  if (wid == 2 || wid == 3) {
    float* r = scratch + (wid-2)*4096;
    #pragma unroll
    for (int i = 0; i < 64; ++i) r[i*64 + lane] = acc[i>>3][i&7];
  }
  __syncthreads();

  if (wid < 2) {
    const float* r = scratch + wid*4096;
    #pragma unroll
    for (int i = 0; i < 64; ++i) acc[i>>3][i&7] += r[i*64 + lane];

    int cbase = bid*128 + chalf*64 + cg*8;
    float myv = 0.f; int myi = 0;
    #pragma unroll
    for (int rr = 0; rr < 8; ++rr) {
      float bv = acc[rr][0] + bo8[0]; int bix = cbase;
      #pragma unroll
      for (int c = 1; c < 8; ++c) {
        float v = acc[rr][c] + bo8[c];
        if (v > bv) { bv = v; bix = cbase + c; }
      }
      #pragma unroll
      for (int m = 1; m < 8; m <<= 1) {
        float ov = __shfl_xor(bv, m, 64);
        int   oi = __shfl_xor(bix, m, 64);
        if (ov > bv || (ov == bv && oi < bix)) { bv = ov; bix = oi; }
      }
      if (cg == rr) { myv = bv; myi = bix; }
    }
    int row = rg*8 + cg;
    u64 kv = ((u64)map_f32(myv) << 32) | (u32)(~(u32)myi);
    atomicMax(&key_cur[row], kv);
  }
}

// ---------------- final token (step T-1) -------------------------------------------------
__global__ void k_final(const int* __restrict__ gnp, const int* __restrict__ input_x,
                        const u64* __restrict__ key_last, const int* __restrict__ tokp,
                        int mode, int* __restrict__ out) {
  int b = threadIdx.x;
  int gn = *gnp;
  int tk;
  if (Tz - 1 < gn) tk = input_x[b*Tz + Tz - 1];
  else             tk = mode ? tokp[b]
                        : (int)(~(u32)(key_last[b] & 0xFFFFFFFFull));
  out[b*Tz + Tz - 1] = tk;
}

extern "C" void kernel_launch(void* const* d_in, const int* in_sizes, int n_in,
                              void* d_out, int out_size, void* d_ws, size_t ws_size,
                              hipStream_t stream) {
  const int*   input_x   = (const int*)d_in[0];
  const int*   gnp       = (const int*)d_in[1];
  const int*   start_tok = (const int*)d_in[2];
  const float* emb = (const float*)d_in[3];
  const float* Wi  = (const float*)d_in[4];
  const float* Ui  = (const float*)d_in[5];
  const float* bi  = (const float*)d_in[6];
  const float* Wf  = (const float*)d_in[7];
  const float* Uf  = (const float*)d_in[8];
  const float* bff = (const float*)d_in[9];
  const float* Wog = (const float*)d_in[10];
  const float* Uog = (const float*)d_in[11];
  const float* bog = (const float*)d_in[12];
  const float* Wc  = (const float*)d_in[13];
  const float* Uc  = (const float*)d_in[14];
  const float* bc  = (const float*)d_in[15];
  const float* Wo  = (const float*)d_in[16];
  const float* bo  = (const float*)d_in[17];
  int* out = (int*)d_out;

  float* wsf  = (float*)d_ws;
  float* hTA  = wsf;                       // 16384 f
  float* hTB  = wsf + 16384;               // 16384 f
  float* cT   = wsf + 32768;               // 16384 f
  u64*   key  = (u64*)(wsf + 49152);       // 256 f
  int*   tok  = (int*)(wsf + 49408);       // 64
  int*   cnt  = (int*)(wsf + 49472);       // 64
  u32*   gmax = (u32*)(wsf + 49536);       // 64
  float* rn2g = wsf + 49600;               // 64
  u32*   wn2  = (u32*)(wsf + 49664);       // 1 (+pad to 49728)
  u16*   hTb  = (u16*)(wsf + 49728);       // 8192 f
  float* P4   = wsf + 57920;               // 327680 f
  u64*   list = (u64*)(wsf + 385600);      // 262144 f (64 x 2048 u64)
  u16*   Wb   = (u16*)(wsf + 647744);      // 4096000 f

  int mode = ws_size >= (size_t)(647744 + 4096000) * 4;

  size_t gsm  = (size_t)(20480 + 5120 + 1024 + 64) * 4;   // 106752 B
  size_t lsmB = 65536;
  size_t lsmF = (size_t)(16384 + 16384) * 4;              // 131072 B
  hipFuncSetAttribute((const void*)k_gates,
                      hipFuncAttributeMaxDynamicSharedMemorySize, (int)gsm);
  hipFuncSetAttribute((const void*)k_logits_b,
                      hipFuncAttributeMaxDynamicSharedMemorySize, (int)lsmB);
  hipFuncSetAttribute((const void*)k_logits_f32,
                      hipFuncAttributeMaxDynamicSharedMemorySize, (int)lsmF);

  k_prep<<<dim3(256), dim3(320), 0, stream>>>(Wi, Ui, Wf, Uf, Wog, Uog, Wc, Uc,
                                              P4, key, cnt, gmax, wn2);
  if (mode)
    wb_prep<<<dim3(250), dim3(512), 0, stream>>>(Wo, Wb, wn2);

  for (int t = 0; t < Tz; ++t) {
    const float* hT_in  = (t & 1) ? hTA : hTB;
    float*       hT_out = (t & 1) ? hTB : hTA;
    const u64* key_prev = key + ((t + 1) & 1) * Bz;
    u64*       key_cur  = key + (t & 1) * Bz;
    k_gates<<<dim3(64), dim3(512), gsm, stream>>>(
        t, gnp, input_x, start_tok, emb, P4, bi, bff, bog, bc,
        hT_in, hT_out, hTb, cT, key_prev, key_cur, tok, mode, out);
    if (mode) {
      k_logits_b<<<dim3(250), dim3(512), lsmB, stream>>>(
          t, gnp, hTb, Wb, bo, wn2, rn2g, gmax, list, cnt);
      k_pick<<<dim3(64), dim3(256), 0, stream>>>(
          t, gnp, hT_out, Wo, bo, wn2, rn2g, list, cnt, gmax, tok);
    } else {
      k_logits_f32<<<dim3(250), dim3(512), lsmF, stream>>>(
          t, gnp, hT_out, Wo, bo, key_cur);
    }
  }
  k_final<<<dim3(1), dim3(64), 0, stream>>>(
      gnp, input_x, key + ((Tz - 1) & 1) * Bz, tok, mode, out);
}

// Round 15
// 731.010 us; speedup vs baseline: 3.0098x; 3.0098x over previous
//
#include <hip/hip_runtime.h>
#include <math.h>
#include <stdint.h>

#define Bz 64
#define Tz 32
#define Ez 64
#define Hz 256
#define Vz 32000
#define KTOT 320

typedef unsigned long long u64;
typedef unsigned int u32;

__device__ __forceinline__ u32 map_f32(float f) {
  u32 u = __float_as_uint(f);
  return (u & 0x80000000u) ? ~u : (u | 0x80000000u);
}

// ---------------- weight repack: P4[j][k][g] (g = i,f,o,c); zero key bufs ----------------
// (byte-identical to round 12's passing k_prep)
__global__ void k_prep(const float* __restrict__ Wi, const float* __restrict__ Ui,
                       const float* __restrict__ Wf, const float* __restrict__ Uf,
                       const float* __restrict__ Wog, const float* __restrict__ Uog,
                       const float* __restrict__ Wc, const float* __restrict__ Uc,
                       float* __restrict__ P4, u64* __restrict__ key) {
  int j = blockIdx.x;        // 0..255
  int k = threadIdx.x;       // 0..319
  float g0, g1, g2, g3;
  if (k < Ez) {
    g0 = Wi[k*Hz + j]; g1 = Wf[k*Hz + j]; g2 = Wog[k*Hz + j]; g3 = Wc[k*Hz + j];
  } else {
    int kk = k - Ez;
    g0 = Ui[kk*Hz + j]; g1 = Uf[kk*Hz + j]; g2 = Uog[kk*Hz + j]; g3 = Uc[kk*Hz + j];
  }
  float* p = P4 + ((size_t)j*KTOT + k)*4;
  p[0] = g0; p[1] = g1; p[2] = g2; p[3] = g3;
  if (j == 0 && k < 2*Bz) key[k] = 0ull;
}

// ---------------- per-step LSTM cell: 64 blocks x 512 thr --------------------------------
// (byte-identical to round 12's passing k_gates)
__global__ __launch_bounds__(512) void k_gates(
    int t, const int* __restrict__ gnp,
    const int* __restrict__ input_x, const int* __restrict__ start_tok,
    const float* __restrict__ emb, const float* __restrict__ P4,
    const float* __restrict__ bi_, const float* __restrict__ bf_,
    const float* __restrict__ bog_, const float* __restrict__ bc_,
    const float* __restrict__ hT_in, float* __restrict__ hT_out,
    float* __restrict__ cT,
    const u64* __restrict__ key_prev, u64* __restrict__ key_cur,
    int* __restrict__ out) {
  extern __shared__ float sm[];
  float* xh = sm;                        // 20480 f : [320][64] transposed
  float* pw = sm + 20480;                // 5120 f  : 4 j x 1280
  float* sc = sm + 25600;                // 1024 f  : merge
  int*   tok_s = (int*)(sm + 26624);     // 64

  int tid = threadIdx.x;
  int blk = blockIdx.x;
  int gn = *gnp;

  if (tid < Bz) {
    int b = tid, tk;
    if (t == 0)          tk = start_tok[b];
    else if (t - 1 < gn) tk = input_x[b*Tz + (t-1)];
    else                 tk = (int)(~(u32)(key_prev[b] & 0xFFFFFFFFull));
    tok_s[b] = tk;
    if (blk == 0 && t > 0) out[b*Tz + (t-1)] = tk;
  }
  if (blk == 0 && tid >= 64 && tid < 64 + Bz) key_cur[tid - 64] = 0ull;
  __syncthreads();

  {
    int b = tid & 63, part = tid >> 6;
    const float4* e4 = (const float4*)(emb + (size_t)tok_s[b]*Ez + part*8);
    float4 v0 = e4[0], v1 = e4[1];
    int k0 = part*8;
    xh[(k0+0)*Bz + b] = v0.x; xh[(k0+1)*Bz + b] = v0.y;
    xh[(k0+2)*Bz + b] = v0.z; xh[(k0+3)*Bz + b] = v0.w;
    xh[(k0+4)*Bz + b] = v1.x; xh[(k0+5)*Bz + b] = v1.y;
    xh[(k0+6)*Bz + b] = v1.z; xh[(k0+7)*Bz + b] = v1.w;
  }
  if (t > 0) {
    const float4* s4 = (const float4*)hT_in;
    float4* d4 = (float4*)(xh + Ez*Bz);
    #pragma unroll
    for (int i = 0; i < 8; ++i) d4[tid + i*512] = s4[tid + i*512];
  }
  {
    const float* psrc = P4 + (size_t)blk*5120;
    #pragma unroll
    for (int i = 0; i < 10; ++i) pw[tid + i*512] = psrc[tid + i*512];
  }
  __syncthreads();

  int wid = tid >> 6, lane = tid & 63;
  int j4 = wid >> 1, seg = wid & 1;
  int j = blk*4 + j4;
  const float* wrow = pw + j4*1280;
  int kbeg = seg ? 160 : 0;
  int kend = (t > 0) ? (seg ? 320 : 160) : (seg ? 0 : 64);

  float ai = 0.f, af = 0.f, ao = 0.f, ac = 0.f;
  #pragma unroll 2
  for (int k = kbeg; k < kend; k += 4) {
    #pragma unroll
    for (int kk = 0; kk < 4; ++kk) {
      float4 wv = *(const float4*)(wrow + (k+kk)*4);
      float xv = xh[(k+kk)*Bz + lane];
      ai = fmaf(xv, wv.x, ai); af = fmaf(xv, wv.y, af);
      ao = fmaf(xv, wv.z, ao); ac = fmaf(xv, wv.w, ac);
    }
  }

  if (seg == 1) {
    sc[j4*256 +   0 + lane] = ai;
    sc[j4*256 +  64 + lane] = af;
    sc[j4*256 + 128 + lane] = ao;
    sc[j4*256 + 192 + lane] = ac;
  }
  __syncthreads();
  if (seg == 0) {
    ai += sc[j4*256 +   0 + lane] + bi_[j];
    af += sc[j4*256 +  64 + lane] + bf_[j];
    ao += sc[j4*256 + 128 + lane] + bog_[j];
    ac += sc[j4*256 + 192 + lane] + bc_[j];
    float gi = 1.f/(1.f + expf(-ai));
    float gf = 1.f/(1.f + expf(-af));
    float go = 1.f/(1.f + expf(-ao));
    float gc = tanhf(ac);
    float cold = (t > 0) ? cT[j*Bz + lane] : 0.f;
    float cn = gf*cold + gi*gc;
    float hn = go * tanhf(cn);
    cT[j*Bz + lane]     = cn;
    hT_out[j*Bz + lane] = hn;
  }
}

// ---------------- logits: 250 blocks x 512 thr; W global->reg, h in LDS ------------------
// wave = (seg = wid>>1 -> k in [seg*64, +64), chalf = wid&1 -> 64 cols)
// lane = (rg = lane>>3 -> 8 rows, cg = lane&7 -> 8 cols); acc[8][8] in registers.
// W loads: per-lane float4 pairs from L2-resident Wo (no LDS staging, no barriers).
__global__ __launch_bounds__(512, 1) void k_logits(
    int t, const int* __restrict__ gnp,
    const float* __restrict__ hT,        // [k][b]
    const float* __restrict__ Wo, const float* __restrict__ bo,
    u64* __restrict__ key_cur) {         // 64 slots
  int gn = *gnp;
  if (t < gn) return;                    // uniform early-exit (teacher step)
  extern __shared__ float sm[];
  float* hLDS = sm;                      // 16384 f (64 KB); reused as merge scratch later

  int tid = threadIdx.x;
  int bid = blockIdx.x;
  int wid = tid >> 6, lane = tid & 63;
  int seg = wid >> 1, chalf = wid & 1;
  int rg = lane >> 3, cg = lane & 7;

  float bo8[8];
  {
    const float4* b4 = (const float4*)(bo + bid*128 + chalf*64 + cg*8);
    float4 x = b4[0], y = b4[1];
    bo8[0]=x.x; bo8[1]=x.y; bo8[2]=x.z; bo8[3]=x.w;
    bo8[4]=y.x; bo8[5]=y.y; bo8[6]=y.z; bo8[7]=y.w;
  }
  // stage hT -> hLDS (coalesced)
  {
    const float4* s4 = (const float4*)hT;
    float4* d4 = (float4*)hLDS;
    #pragma unroll
    for (int i = 0; i < 8; ++i) d4[tid + i*512] = s4[tid + i*512];
  }
  __syncthreads();

  float acc[8][8] = {};
  // per-lane W column base: this wave's 64-col half, lane's 8 cols
  const float* gW = Wo + (size_t)(seg*64)*Vz + bid*128 + chalf*64 + cg*8;
  const float* hp = hLDS + (seg*64)*Bz + rg*8;

  #pragma unroll 4
  for (int k = 0; k < 64; ++k) {
    float4 w0 = *(const float4*)(gW + (size_t)k*Vz);
    float4 w1 = *(const float4*)(gW + (size_t)k*Vz + 4);
    float4 h0 = *(const float4*)(hp + k*Bz);
    float4 h1 = *(const float4*)(hp + k*Bz + 4);
    float hv[8] = {h0.x,h0.y,h0.z,h0.w,h1.x,h1.y,h1.z,h1.w};
    float wv[8] = {w0.x,w0.y,w0.z,w0.w,w1.x,w1.y,w1.z,w1.w};
    #pragma unroll
    for (int r = 0; r < 8; ++r) {
      #pragma unroll
      for (int c = 0; c < 8; ++c) acc[r][c] = fmaf(hv[r], wv[c], acc[r][c]);
    }
  }

  // ---- merge k-segment partials: (seg2,seg3) -> (seg0,seg1), then seg1 -> seg0 ----
  float* scratch = hLDS;                 // 4 regions x 4096 f (h no longer needed)
  __syncthreads();                       // all waves done reading hLDS
  if (wid >= 4) {
    float* r = scratch + (wid-4)*4096;
    #pragma unroll
    for (int i = 0; i < 64; ++i) r[i*64 + lane] = acc[i>>3][i&7];
  }
  __syncthreads();
  if (wid < 4) {
    const float* r = scratch + wid*4096;
    #pragma unroll
    for (int i = 0; i < 64; ++i) acc[i>>3][i&7] += r[i*64 + lane];
  }
  __syncthreads();
  if (wid == 2 || wid == 3) {
    float* r = scratch + (wid-2)*4096;
    #pragma unroll
    for (int i = 0; i < 64; ++i) r[i*64 + lane] = acc[i>>3][i&7];
  }
  __syncthreads();

  if (wid < 2) {
    const float* r = scratch + wid*4096;
    #pragma unroll
    for (int i = 0; i < 64; ++i) acc[i>>3][i&7] += r[i*64 + lane];

    // per-row argmax over this wave's 64 cols; first-index-wins
    int cbase = bid*128 + chalf*64 + cg*8;
    float myv = 0.f; int myi = 0;
    #pragma unroll
    for (int rr = 0; rr < 8; ++rr) {
      float bv = acc[rr][0] + bo8[0]; int bix = cbase;
      #pragma unroll
      for (int c = 1; c < 8; ++c) {
        float v = acc[rr][c] + bo8[c];
        if (v > bv) { bv = v; bix = cbase + c; }
      }
      #pragma unroll
      for (int m = 1; m < 8; m <<= 1) {
        float ov = __shfl_xor(bv, m, 64);
        int   oi = __shfl_xor(bix, m, 64);
        if (ov > bv || (ov == bv && oi < bix)) { bv = ov; bix = oi; }
      }
      if (cg == rr) { myv = bv; myi = bix; }
    }
    int row = rg*8 + cg;
    u64 kv = ((u64)map_f32(myv) << 32) | (u32)(~(u32)myi);
    atomicMax(&key_cur[row], kv);
  }
}

// ---------------- final token (step T-1) -------------------------------------------------
// (byte-identical to round 12's passing k_final)
__global__ void k_final(const int* __restrict__ gnp, const int* __restrict__ input_x,
                        const u64* __restrict__ key_last, int* __restrict__ out) {
  int b = threadIdx.x;
  int gn = *gnp;
  int tk;
  if (Tz - 1 < gn) tk = input_x[b*Tz + Tz - 1];
  else             tk = (int)(~(u32)(key_last[b] & 0xFFFFFFFFull));
  out[b*Tz + Tz - 1] = tk;
}

extern "C" void kernel_launch(void* const* d_in, const int* in_sizes, int n_in,
                              void* d_out, int out_size, void* d_ws, size_t ws_size,
                              hipStream_t stream) {
  const int*   input_x   = (const int*)d_in[0];
  const int*   gnp       = (const int*)d_in[1];
  const int*   start_tok = (const int*)d_in[2];
  const float* emb = (const float*)d_in[3];
  const float* Wi  = (const float*)d_in[4];
  const float* Ui  = (const float*)d_in[5];
  const float* bi  = (const float*)d_in[6];
  const float* Wf  = (const float*)d_in[7];
  const float* Uf  = (const float*)d_in[8];
  const float* bff = (const float*)d_in[9];
  const float* Wog = (const float*)d_in[10];
  const float* Uog = (const float*)d_in[11];
  const float* bog = (const float*)d_in[12];
  const float* Wc  = (const float*)d_in[13];
  const float* Uc  = (const float*)d_in[14];
  const float* bc  = (const float*)d_in[15];
  const float* Wo  = (const float*)d_in[16];
  const float* bo  = (const float*)d_in[17];
  int* out = (int*)d_out;

  float* wsf = (float*)d_ws;
  float* hTA = wsf;                      // 16384 f
  float* hTB = wsf + 16384;              // 16384 f
  float* cT  = wsf + 32768;              // 16384 f
  u64*   key = (u64*)(wsf + 49152);      // 128 u64 = 256 f
  float* P4  = wsf + 49152 + 256;        // 327680 f

  size_t gsm = (size_t)(20480 + 5120 + 1024 + 64) * 4;   // 106752 B
  size_t lsm = (size_t)16384 * 4;                        // 65536 B
  hipFuncSetAttribute((const void*)k_gates,
                      hipFuncAttributeMaxDynamicSharedMemorySize, (int)gsm);
  hipFuncSetAttribute((const void*)k_logits,
                      hipFuncAttributeMaxDynamicSharedMemorySize, (int)lsm);

  k_prep<<<dim3(256), dim3(320), 0, stream>>>(Wi, Ui, Wf, Uf, Wog, Uog, Wc, Uc, P4, key);

  for (int t = 0; t < Tz; ++t) {
    const float* hT_in  = (t & 1) ? hTA : hTB;
    float*       hT_out = (t & 1) ? hTB : hTA;
    const u64* key_prev = key + ((t + 1) & 1) * Bz;
    u64*       key_cur  = key + (t & 1) * Bz;
    k_gates<<<dim3(64), dim3(512), gsm, stream>>>(
        t, gnp, input_x, start_tok, emb, P4, bi, bff, bog, bc,
        hT_in, hT_out, cT, key_prev, key_cur, out);
    k_logits<<<dim3(250), dim3(512), lsm, stream>>>(
        t, gnp, hT_out, Wo, bo, key_cur);
  }
  k_final<<<dim3(1), dim3(64), 0, stream>>>(
      gnp, input_x, key + ((Tz - 1) & 1) * Bz, out);
}